// Round 7
// baseline (266.878 us; speedup 1.0000x reference)
//
#include <hip/hip_runtime.h>
#include <hip/hip_bf16.h>
#include <math.h>

#define N_NODES 50000
#define N_EDGES 800000
#define HEADS 4
#define HID 32
#define D1 128
#define D2 64
#define NEG_SLOPE 0.2f
#define LN_EPS 1e-5f

#define NB_SCAN ((N_NODES + 255) / 256)  // 196
#define CAP 64
#define GB1 (((N_NODES + 127) / 128) * 2)  // 782: 391 row-blocks x 2 col-halves
#define DEGB 784

__device__ __forceinline__ float lrelu(float x) { return x > 0.f ? x : NEG_SLOPE * x; }
__device__ __forceinline__ float bf2f(__hip_bfloat16 v) { return __bfloat162float(v); }

// ---------------- K1: gemm1 (+att1 epilogue) fused with degree/rank ----------------
// Block: 128 rows x 64 cols (one half). Lane owns 4 consecutive rows x 8 cols.
// X staged via LDS transposed ([k][row]) in 32-k chunks: global loads fully
// coalesced (16 lines/instr), lane reads rows as one ds_read_b128.
// W-half (32 KB) staged once; reads (half-)wave-uniform -> broadcast.
__global__ __launch_bounds__(256) void gemm1_att1_degree_kernel(
    const float* __restrict__ X, const float* __restrict__ W,
    __hip_bfloat16* __restrict__ Y,
    const float* __restrict__ att_src, const float* __restrict__ att_dst,
    float* __restrict__ a_s, float* __restrict__ a_d,
    const int* __restrict__ dst, int* __restrict__ deg, int* __restrict__ rank) {
    __shared__ float Wlds[128 * 64];   // 32 KB [k][c]
    __shared__ float Xlds[32][132];    // 16.5 KB [k][row], padded
    if (blockIdx.x >= GB1) {
        int t0 = (blockIdx.x - GB1) * 256 + threadIdx.x;
        const int stride = DEGB * 256;
#pragma unroll
        for (int u = 0; u < 4; ++u) {
            int i = t0 + u * stride;
            if (i < N_EDGES) rank[i] = atomicAdd(&deg[dst[i]], 1);
        }
        return;
    }
    int tid = threadIdx.x;
    int rb = blockIdx.x >> 1;
    int half = blockIdx.x & 1;
    int wv = tid >> 6;
    int lane = tid & 63;
    int rl = lane & 31;            // row-lane: rows 4*rl..4*rl+3
    int ch = lane >> 5;            // col sub-group within wave
    int c0 = wv * 16 + ch * 8;     // col within 64-half
    int gc0 = half * 64 + c0;      // global col (also att1 flat index base)
    int r0 = rb * 128;
    int rowbase = rl * 4;

    for (int idx = tid; idx < 128 * 16; idx += 256) {
        int k = idx >> 4, c4 = idx & 15;
        *(float4*)&Wlds[k * 64 + c4 * 4] =
            *(const float4*)&W[(size_t)k * 128 + half * 64 + c4 * 4];
    }

    float acc[4][8];
#pragma unroll
    for (int i = 0; i < 4; ++i)
#pragma unroll
        for (int j = 0; j < 8; ++j) acc[i][j] = 0.f;

    for (int kb = 0; kb < 128; kb += 32) {
        __syncthreads();  // previous chunk fully consumed (also covers W staging)
        // stage X chunk: rows r0..r0+127, k in [kb, kb+32), transposed
        for (int i = tid; i < 1024; i += 256) {
            int row = i >> 3;
            int kq = i & 7;
            int rr = r0 + row; if (rr >= N_NODES) rr = N_NODES - 1;
            float4 v = *(const float4*)&X[(size_t)rr * 128 + kb + kq * 4];
            Xlds[kq * 4 + 0][row] = v.x;
            Xlds[kq * 4 + 1][row] = v.y;
            Xlds[kq * 4 + 2][row] = v.z;
            Xlds[kq * 4 + 3][row] = v.w;
        }
        __syncthreads();
#pragma unroll 8
        for (int k = 0; k < 32; ++k) {
            float4 xv = *(const float4*)&Xlds[k][rowbase];
            const float* wrow = &Wlds[(kb + k) * 64 + c0];
            const float4 w0 = *(const float4*)(wrow + 0);
            const float4 w1 = *(const float4*)(wrow + 4);
#pragma unroll
            for (int i = 0; i < 4; ++i) {
                float xk = (i == 0) ? xv.x : (i == 1) ? xv.y : (i == 2) ? xv.z : xv.w;
                acc[i][0] += xk * w0.x; acc[i][1] += xk * w0.y;
                acc[i][2] += xk * w0.z; acc[i][3] += xk * w0.w;
                acc[i][4] += xk * w1.x; acc[i][5] += xk * w1.y;
                acc[i][6] += xk * w1.z; acc[i][7] += xk * w1.w;
            }
        }
    }

    // h1pre bf16 store: lane rows 4rl..4rl+3, cols gc0..gc0+7
#pragma unroll
    for (int i = 0; i < 4; ++i) {
        int r = r0 + rowbase + i;
        if (r < N_NODES) {
            __hip_bfloat162* yp = (__hip_bfloat162*)(Y + (size_t)r * 128 + gc0);
#pragma unroll
            for (int j = 0; j < 4; ++j) {
                __hip_bfloat162 p;
                p.x = __float2bfloat16(acc[i][2 * j]);
                p.y = __float2bfloat16(acc[i][2 * j + 1]);
                yp[j] = p;
            }
        }
    }

    // att1: per-lane partial over 8 cols (att flat index == global col), then
    // shfl_xor(32) within wave, then cross-wave-pair reduce via LDS scratch.
    float ps[4], pd[4];
#pragma unroll
    for (int i = 0; i < 4; ++i) {
        ps[i] = 0.f; pd[i] = 0.f;
#pragma unroll
        for (int j = 0; j < 8; ++j) {
            ps[i] += acc[i][j] * att_src[gc0 + j];
            pd[i] += acc[i][j] * att_dst[gc0 + j];
        }
        ps[i] += __shfl_xor(ps[i], 32, 64);
        pd[i] += __shfl_xor(pd[i], 32, 64);
    }
    __syncthreads();  // done reading Xlds -> reuse as scratch
    float* red = &Xlds[0][0];
    if (ch == 0) {
#pragma unroll
        for (int i = 0; i < 4; ++i) {
            red[wv * 128 + rowbase + i] = ps[i];
            red[512 + wv * 128 + rowbase + i] = pd[i];
        }
    }
    __syncthreads();
    if (tid < 128) {
        int r = r0 + tid;
        if (r < N_NODES) {
            float as0 = red[tid] + red[128 + tid];
            float as1 = red[256 + tid] + red[384 + tid];
            float ad0 = red[512 + tid] + red[640 + tid];
            float ad1 = red[768 + tid] + red[896 + tid];
            a_s[r * 4 + half * 2 + 0] = as0;
            a_s[r * 4 + half * 2 + 1] = as1;
            a_d[r * 4 + half * 2 + 0] = ad0;
            a_d[r * 4 + half * 2 + 1] = ad1;
        }
    }
}

// ---------------- scans ----------------
__global__ __launch_bounds__(256) void scan1_kernel(const int* __restrict__ deg,
                                                    int* __restrict__ rpl,
                                                    int* __restrict__ bsum) {
    int i = blockIdx.x * 256 + threadIdx.x;
    int v = (i < N_NODES) ? deg[i] : 0;
    int lane = threadIdx.x & 63;
    int w = threadIdx.x >> 6;
    int x = v;
#pragma unroll
    for (int off = 1; off < 64; off <<= 1) {
        int t = __shfl_up(x, off, 64);
        if (lane >= off) x += t;
    }
    __shared__ int wsum[4];
    if (lane == 63) wsum[w] = x;
    __syncthreads();
    int wo = 0;
    if (w > 0) wo += wsum[0];
    if (w > 1) wo += wsum[1];
    if (w > 2) wo += wsum[2];
    if (i <= N_NODES) rpl[i] = x - v + wo;
    if (threadIdx.x == 255) bsum[blockIdx.x] = x + wo;
}

__global__ __launch_bounds__(256) void scan2_kernel(const int* __restrict__ bsum,
                                                    int* __restrict__ boff) {
    int i = threadIdx.x;
    int v = (i < NB_SCAN) ? bsum[i] : 0;
    int lane = threadIdx.x & 63;
    int w = threadIdx.x >> 6;
    int x = v;
#pragma unroll
    for (int off = 1; off < 64; off <<= 1) {
        int t = __shfl_up(x, off, 64);
        if (lane >= off) x += t;
    }
    __shared__ int wsum[4];
    if (lane == 63) wsum[w] = x;
    __syncthreads();
    int wo = 0;
    if (w > 0) wo += wsum[0];
    if (w > 1) wo += wsum[1];
    if (w > 2) wo += wsum[2];
    if (i < NB_SCAN) boff[i] = x - v + wo;
}

// ---------------- scatter ----------------
__global__ __launch_bounds__(256) void scatter_kernel(const int* __restrict__ src,
                                                      const int* __restrict__ dst,
                                                      const int* __restrict__ rpl,
                                                      const int* __restrict__ boff,
                                                      const int* __restrict__ rank,
                                                      int* __restrict__ col) {
    int i = blockIdx.x * blockDim.x + threadIdx.x;
    if (i < N_EDGES) {
        int d = dst[i];
        int pos = rpl[d] + boff[d >> 8] + rank[i];
        col[pos] = src[i];
    }
}

// ---------------- aggregation layer 1 ----------------
__global__ __launch_bounds__(256) void agg1_kernel(const __hip_bfloat16* __restrict__ h,
                                                   const float* __restrict__ a_s,
                                                   const float* __restrict__ a_d,
                                                   const int* __restrict__ rpl,
                                                   const int* __restrict__ boff,
                                                   const int* __restrict__ col,
                                                   const float* __restrict__ b1,
                                                   const float* __restrict__ gamma,
                                                   const float* __restrict__ beta,
                                                   float* __restrict__ out) {
    __shared__ int colsh[4][CAP];
    __shared__ float wsh[4][CAP * 4];
    int wv = threadIdx.x >> 6;
    int lane = threadIdx.x & 63;
    int n = blockIdx.x * 4 + wv;
    int nn = (n < N_NODES) ? n : N_NODES - 1;
    int head = lane >> 4;
    int c = 2 * lane;

    const float4 ad4 = *(const float4*)&a_d[nn * 4];
    int beg = rpl[nn] + boff[nn >> 8];
    int end = rpl[nn + 1] + boff[(nn + 1) >> 8];
    int deg = end - beg;

    float den0 = 0.f, den1 = 0.f, den2 = 0.f, den3 = 0.f;
    for (int t = lane; t < deg; t += 64) {
        int s = col[beg + t];
        const float4 as4 = *(const float4*)&a_s[s * 4];
        float w0 = __expf(lrelu(as4.x + ad4.x));
        float w1 = __expf(lrelu(as4.y + ad4.y));
        float w2 = __expf(lrelu(as4.z + ad4.z));
        float w3 = __expf(lrelu(as4.w + ad4.w));
        if (t < CAP) {
            colsh[wv][t] = s;
            *(float4*)&wsh[wv][t * 4] = make_float4(w0, w1, w2, w3);
        }
        den0 += w0; den1 += w1; den2 += w2; den3 += w3;
    }
#pragma unroll
    for (int m = 1; m < 64; m <<= 1) {
        den0 += __shfl_xor(den0, m, 64);
        den1 += __shfl_xor(den1, m, 64);
        den2 += __shfl_xor(den2, m, 64);
        den3 += __shfl_xor(den3, m, 64);
    }
    float adh = (head == 0) ? ad4.x : (head == 1) ? ad4.y : (head == 2) ? ad4.z : ad4.w;
    float wself = __expf(lrelu(a_s[nn * 4 + head] + adh));
    float den = ((head == 0) ? den0 : (head == 1) ? den1 : (head == 2) ? den2 : den3) + wself;

    __syncthreads();

    float ax0 = 0.f, ay0 = 0.f, ax1 = 0.f, ay1 = 0.f;
    int m0 = (deg < CAP) ? deg : CAP;
    int j = 0;
    for (; j + 3 < m0; j += 4) {
        int s0 = colsh[wv][j + 0], s1 = colsh[wv][j + 1];
        int s2 = colsh[wv][j + 2], s3 = colsh[wv][j + 3];
        float w0 = wsh[wv][(j + 0) * 4 + head], w1 = wsh[wv][(j + 1) * 4 + head];
        float w2 = wsh[wv][(j + 2) * 4 + head], w3 = wsh[wv][(j + 3) * 4 + head];
        __hip_bfloat162 h0 = ((const __hip_bfloat162*)h)[(size_t)s0 * 64 + lane];
        __hip_bfloat162 h1 = ((const __hip_bfloat162*)h)[(size_t)s1 * 64 + lane];
        __hip_bfloat162 h2v = ((const __hip_bfloat162*)h)[(size_t)s2 * 64 + lane];
        __hip_bfloat162 h3 = ((const __hip_bfloat162*)h)[(size_t)s3 * 64 + lane];
        ax0 += w0 * bf2f(h0.x); ay0 += w0 * bf2f(h0.y);
        ax1 += w1 * bf2f(h1.x); ay1 += w1 * bf2f(h1.y);
        ax0 += w2 * bf2f(h2v.x); ay0 += w2 * bf2f(h2v.y);
        ax1 += w3 * bf2f(h3.x); ay1 += w3 * bf2f(h3.y);
    }
    for (; j < m0; ++j) {
        int s = colsh[wv][j];
        float w = wsh[wv][j * 4 + head];
        __hip_bfloat162 hv = ((const __hip_bfloat162*)h)[(size_t)s * 64 + lane];
        ax0 += w * bf2f(hv.x); ay0 += w * bf2f(hv.y);
    }
    for (; j < deg; ++j) {
        int s = col[beg + j];
        float w = __expf(lrelu(a_s[s * 4 + head] + adh));
        __hip_bfloat162 hv = ((const __hip_bfloat162*)h)[(size_t)s * 64 + lane];
        ax0 += w * bf2f(hv.x); ay0 += w * bf2f(hv.y);
    }
    {
        __hip_bfloat162 hv = ((const __hip_bfloat162*)h)[(size_t)nn * 64 + lane];
        ax0 += wself * bf2f(hv.x); ay0 += wself * bf2f(hv.y);
    }
    float inv = 1.f / den;
    float vx = (ax0 + ax1) * inv + b1[c];
    float vy = (ay0 + ay1) * inv + b1[c + 1];

    float s1 = vx + vy, s2 = vx * vx + vy * vy;
#pragma unroll
    for (int m = 1; m < 64; m <<= 1) {
        s1 += __shfl_xor(s1, m, 64);
        s2 += __shfl_xor(s2, m, 64);
    }
    float mean = s1 * (1.f / 128.f);
    float var = s2 * (1.f / 128.f) - mean * mean;
    float r = rsqrtf(var + LN_EPS);
    float ox = fmaxf(0.f, (vx - mean) * r * gamma[c] + beta[c]);
    float oy = fmaxf(0.f, (vy - mean) * r * gamma[c + 1] + beta[c + 1]);
    if (n < N_NODES) *(float2*)&out[(size_t)n * 128 + c] = make_float2(ox, oy);
}

// ---------------- gemm2 + att2 epilogue (same X-LDS-staged structure) ----------------
__global__ __launch_bounds__(256) void gemm2_att2_kernel(const float* __restrict__ X,
                                                         const float* __restrict__ W,
                                                         __hip_bfloat16* __restrict__ Y,
                                                         const float* __restrict__ att_src,
                                                         const float* __restrict__ att_dst,
                                                         float* __restrict__ a_s,
                                                         float* __restrict__ a_d) {
    __shared__ float Wlds[128 * 64];   // whole W2, 32 KB
    __shared__ float Xlds[32][132];
    int tid = threadIdx.x;
    int wv = tid >> 6;
    int lane = tid & 63;
    int rl = lane & 31;
    int ch = lane >> 5;
    int c0 = wv * 16 + ch * 8;
    int r0 = blockIdx.x * 128;
    int rowbase = rl * 4;

    for (int idx = tid; idx < 128 * 16; idx += 256)
        ((float4*)Wlds)[idx] = ((const float4*)W)[idx];

    float acc[4][8];
#pragma unroll
    for (int i = 0; i < 4; ++i)
#pragma unroll
        for (int j = 0; j < 8; ++j) acc[i][j] = 0.f;

    for (int kb = 0; kb < 128; kb += 32) {
        __syncthreads();
        for (int i = tid; i < 1024; i += 256) {
            int row = i >> 3;
            int kq = i & 7;
            int rr = r0 + row; if (rr >= N_NODES) rr = N_NODES - 1;
            float4 v = *(const float4*)&X[(size_t)rr * 128 + kb + kq * 4];
            Xlds[kq * 4 + 0][row] = v.x;
            Xlds[kq * 4 + 1][row] = v.y;
            Xlds[kq * 4 + 2][row] = v.z;
            Xlds[kq * 4 + 3][row] = v.w;
        }
        __syncthreads();
#pragma unroll 8
        for (int k = 0; k < 32; ++k) {
            float4 xv = *(const float4*)&Xlds[k][rowbase];
            const float* wrow = &Wlds[(kb + k) * 64 + c0];
            const float4 w0 = *(const float4*)(wrow + 0);
            const float4 w1 = *(const float4*)(wrow + 4);
#pragma unroll
            for (int i = 0; i < 4; ++i) {
                float xk = (i == 0) ? xv.x : (i == 1) ? xv.y : (i == 2) ? xv.z : xv.w;
                acc[i][0] += xk * w0.x; acc[i][1] += xk * w0.y;
                acc[i][2] += xk * w0.z; acc[i][3] += xk * w0.w;
                acc[i][4] += xk * w1.x; acc[i][5] += xk * w1.y;
                acc[i][6] += xk * w1.z; acc[i][7] += xk * w1.w;
            }
        }
    }

#pragma unroll
    for (int i = 0; i < 4; ++i) {
        int r = r0 + rowbase + i;
        if (r < N_NODES) {
            __hip_bfloat162* yp = (__hip_bfloat162*)(Y + (size_t)r * 64 + c0);
#pragma unroll
            for (int j = 0; j < 4; ++j) {
                __hip_bfloat162 p;
                p.x = __float2bfloat16(acc[i][2 * j]);
                p.y = __float2bfloat16(acc[i][2 * j + 1]);
                yp[j] = p;
            }
        }
    }

    float ps[4], pd[4];
#pragma unroll
    for (int i = 0; i < 4; ++i) {
        ps[i] = 0.f; pd[i] = 0.f;
#pragma unroll
        for (int j = 0; j < 8; ++j) {
            ps[i] += acc[i][j] * att_src[c0 + j];
            pd[i] += acc[i][j] * att_dst[c0 + j];
        }
        ps[i] += __shfl_xor(ps[i], 32, 64);
        pd[i] += __shfl_xor(pd[i], 32, 64);
    }
    __syncthreads();
    float* red = &Xlds[0][0];
    if (ch == 0) {
#pragma unroll
        for (int i = 0; i < 4; ++i) {
            red[wv * 128 + rowbase + i] = ps[i];
            red[512 + wv * 128 + rowbase + i] = pd[i];
        }
    }
    __syncthreads();
    if (tid < 128) {
        int r = r0 + tid;
        if (r < N_NODES) {
            float as = red[tid] + red[128 + tid] + red[256 + tid] + red[384 + tid];
            float ad = red[512 + tid] + red[640 + tid] + red[768 + tid] + red[896 + tid];
            a_s[r] = as;
            a_d[r] = ad;
        }
    }
}

// ---------------- aggregation layer 2 ----------------
__global__ __launch_bounds__(256) void agg2_kernel(const __hip_bfloat16* __restrict__ h,
                                                   const float* __restrict__ a_s,
                                                   const float* __restrict__ a_d,
                                                   const int* __restrict__ rpl,
                                                   const int* __restrict__ boff,
                                                   const int* __restrict__ col,
                                                   const float* __restrict__ b2,
                                                   const float* __restrict__ gamma,
                                                   const float* __restrict__ beta,
                                                   float* __restrict__ out) {
    __shared__ int colsh[4][CAP];
    __shared__ float wsh[4][CAP];
    int wv = threadIdx.x >> 6;
    int lane = threadIdx.x & 63;
    int n = blockIdx.x * 4 + wv;
    int nn = (n < N_NODES) ? n : N_NODES - 1;

    float adh = a_d[nn];
    int beg = rpl[nn] + boff[nn >> 8];
    int end = rpl[nn + 1] + boff[(nn + 1) >> 8];
    int deg = end - beg;

    float den = 0.f;
    for (int t = lane; t < deg; t += 64) {
        int s = col[beg + t];
        float w = __expf(lrelu(a_s[s] + adh));
        if (t < CAP) {
            colsh[wv][t] = s;
            wsh[wv][t] = w;
        }
        den += w;
    }
#pragma unroll
    for (int m = 1; m < 64; m <<= 1) den += __shfl_xor(den, m, 64);
    float wself = __expf(lrelu(a_s[nn] + adh));
    den += wself;

    __syncthreads();

    float a0 = 0.f, a1 = 0.f;
    int m0 = (deg < CAP) ? deg : CAP;
    int j = 0;
    for (; j + 3 < m0; j += 4) {
        int s0 = colsh[wv][j + 0], s1 = colsh[wv][j + 1];
        int s2 = colsh[wv][j + 2], s3 = colsh[wv][j + 3];
        float w0 = wsh[wv][j + 0], w1 = wsh[wv][j + 1];
        float w2 = wsh[wv][j + 2], w3 = wsh[wv][j + 3];
        a0 += w0 * bf2f(h[(size_t)s0 * 64 + lane]);
        a1 += w1 * bf2f(h[(size_t)s1 * 64 + lane]);
        a0 += w2 * bf2f(h[(size_t)s2 * 64 + lane]);
        a1 += w3 * bf2f(h[(size_t)s3 * 64 + lane]);
    }
    for (; j < m0; ++j) {
        a0 += wsh[wv][j] * bf2f(h[(size_t)colsh[wv][j] * 64 + lane]);
    }
    for (; j < deg; ++j) {
        int s = col[beg + j];
        float w = __expf(lrelu(a_s[s] + adh));
        a0 += w * bf2f(h[(size_t)s * 64 + lane]);
    }
    a0 += wself * bf2f(h[(size_t)nn * 64 + lane]);

    float v = (a0 + a1) / den + b2[lane];

    float s1 = v, s2 = v * v;
#pragma unroll
    for (int m = 1; m < 64; m <<= 1) {
        s1 += __shfl_xor(s1, m, 64);
        s2 += __shfl_xor(s2, m, 64);
    }
    float mean = s1 * (1.f / 64.f);
    float var = s2 * (1.f / 64.f) - mean * mean;
    float r = rsqrtf(var + LN_EPS);
    if (n < N_NODES) out[(size_t)n * 64 + lane] = (v - mean) * r * gamma[lane] + beta[lane];
}

// ---------------- host ----------------
extern "C" void kernel_launch(void* const* d_in, const int* in_sizes, int n_in,
                              void* d_out, int out_size, void* d_ws, size_t ws_size,
                              hipStream_t stream) {
    const float* x        = (const float*)d_in[0];
    const int*   ei       = (const int*)d_in[1];
    const float* W1       = (const float*)d_in[2];
    const float* att_src1 = (const float*)d_in[3];
    const float* att_dst1 = (const float*)d_in[4];
    const float* b1       = (const float*)d_in[5];
    const float* gamma1   = (const float*)d_in[6];
    const float* beta1    = (const float*)d_in[7];
    const float* W2       = (const float*)d_in[8];
    const float* att_src2 = (const float*)d_in[9];
    const float* att_dst2 = (const float*)d_in[10];
    const float* b2       = (const float*)d_in[11];
    const float* gamma2   = (const float*)d_in[12];
    const float* beta2    = (const float*)d_in[13];
    const int* src = ei;
    const int* dst = ei + N_EDGES;
    float* out = (float*)d_out;

    char* ws = (char*)d_ws;
    size_t off = 0;
    auto alloc = [&](size_t bytes) -> void* {
        void* p = ws + off;
        off += bytes;
        off = (off + 255) & ~(size_t)255;
        return p;
    };
    __hip_bfloat16* h1pre = (__hip_bfloat16*)alloc((size_t)N_NODES * 128 * 2);
    __hip_bfloat16* h2pre = (__hip_bfloat16*)alloc((size_t)N_NODES * 64 * 2);
    float* a_s1   = (float*)alloc((size_t)N_NODES * 4 * 4);
    float* a_d1   = (float*)alloc((size_t)N_NODES * 4 * 4);
    float* h1n    = (float*)alloc((size_t)N_NODES * 128 * 4);
    float* a_s2   = (float*)alloc((size_t)N_NODES * 4);
    float* a_d2   = (float*)alloc((size_t)N_NODES * 4);
    int* deg      = (int*)alloc((size_t)N_NODES * 4);
    int* rpl      = (int*)alloc((size_t)(N_NODES + 1) * 4);
    int* col      = (int*)alloc((size_t)N_EDGES * 4);
    int* rank     = (int*)alloc((size_t)N_EDGES * 4);
    int* bsum     = (int*)alloc((size_t)NB_SCAN * 4);
    int* boff     = (int*)alloc((size_t)NB_SCAN * 4);

    hipMemsetAsync(deg, 0, (size_t)N_NODES * 4, stream);

    const int EB = (N_EDGES + 255) / 256;
    const int NWB = (N_NODES + 3) / 4;

    gemm1_att1_degree_kernel<<<GB1 + DEGB, 256, 0, stream>>>(
        x, W1, h1pre, att_src1, att_dst1, a_s1, a_d1, dst, deg, rank);
    scan1_kernel<<<NB_SCAN, 256, 0, stream>>>(deg, rpl, bsum);
    scan2_kernel<<<1, 256, 0, stream>>>(bsum, boff);
    scatter_kernel<<<EB, 256, 0, stream>>>(src, dst, rpl, boff, rank, col);

    agg1_kernel<<<NWB, 256, 0, stream>>>(h1pre, a_s1, a_d1, rpl, boff, col, b1, gamma1, beta1, h1n);

    gemm2_att2_kernel<<<(N_NODES + 127) / 128, 256, 0, stream>>>(
        h1n, W2, h2pre, att_src2, att_dst2, a_s2, a_d2);
    agg2_kernel<<<NWB, 256, 0, stream>>>(h2pre, a_s2, a_d2, rpl, boff, col, b2, gamma2, beta2, out);
}

// Round 8
// 253.134 us; speedup vs baseline: 1.0543x; 1.0543x over previous
//
#include <hip/hip_runtime.h>
#include <hip/hip_bf16.h>
#include <math.h>

#define N_NODES 50000
#define N_EDGES 800000
#define HEADS 4
#define HID 32
#define D1 128
#define D2 64
#define NEG_SLOPE 0.2f
#define LN_EPS 1e-5f

#define NB_SCAN ((N_NODES + 255) / 256)   // 196
#define CAP 64
#define GB1 ((N_NODES + 255) / 256)       // 196 gemm blocks (512 thr, 256 rows each)
#define DEGB 391                           // degree blocks (512 thr, 4 edges/thread)

__device__ __forceinline__ float lrelu(float x) { return x > 0.f ? x : NEG_SLOPE * x; }
__device__ __forceinline__ float bf2f(__hip_bfloat16 v) { return __bfloat162float(v); }

// ---------------- K1: gemm1 (+att1 epilogue) fused with degree/rank ----------------
// R4-proven structure, widened to 512 threads / 256 rows per block:
// same 64 KB W LDS now hosts 8 waves instead of 4 -> 16 waves/CU (was 8).
// cg = tid%8: 8 lanes share each X row-quad -> X float4 loads touch 8 lines/wave.
__global__ __launch_bounds__(512) void gemm1_att1_degree_kernel(
    const float* __restrict__ X, const float* __restrict__ W,
    __hip_bfloat16* __restrict__ Y,
    const float* __restrict__ att_src, const float* __restrict__ att_dst,
    float* __restrict__ a_s, float* __restrict__ a_d,
    const int* __restrict__ dst, int* __restrict__ deg, int* __restrict__ rank) {
    __shared__ float Wlds[128 * 128];  // 64 KB
    if (blockIdx.x >= GB1) {
        int t0 = (blockIdx.x - GB1) * 512 + threadIdx.x;
        const int stride = DEGB * 512;
#pragma unroll
        for (int u = 0; u < 4; ++u) {
            int i = t0 + u * stride;
            if (i < N_EDGES) rank[i] = atomicAdd(&deg[dst[i]], 1);
        }
        return;
    }
    int tid = threadIdx.x;
    int cg = tid % 8;            // col group (16 cols); pair (cg, cg^1) = one head
    int rg = tid / 8;            // 0..63 -> 4 rows each
    int c0 = cg * 16;
    int r0 = blockIdx.x * 256 + rg * 4;

    for (int i = tid; i < 128 * 128; i += 512) Wlds[i] = W[i];
    __syncthreads();

    float acc[4][16];
#pragma unroll
    for (int i = 0; i < 4; ++i)
#pragma unroll
        for (int j = 0; j < 16; ++j) acc[i][j] = 0.f;

    const float* xrow[4];
#pragma unroll
    for (int i = 0; i < 4; ++i) {
        int ri = r0 + i;
        if (ri >= N_NODES) ri = N_NODES - 1;
        xrow[i] = X + (size_t)ri * 128;
    }

    for (int k = 0; k < 128; k += 4) {
        float4 xv[4];
#pragma unroll
        for (int i = 0; i < 4; ++i) xv[i] = *(const float4*)&xrow[i][k];
#pragma unroll
        for (int kk = 0; kk < 4; ++kk) {
            const float* wrow = &Wlds[(k + kk) * 128 + c0];
            const float4 w0 = *(const float4*)(wrow + 0);
            const float4 w1 = *(const float4*)(wrow + 4);
            const float4 w2 = *(const float4*)(wrow + 8);
            const float4 w3 = *(const float4*)(wrow + 12);
#pragma unroll
            for (int i = 0; i < 4; ++i) {
                float xk = (kk == 0) ? xv[i].x : (kk == 1) ? xv[i].y : (kk == 2) ? xv[i].z : xv[i].w;
                acc[i][0]  += xk * w0.x; acc[i][1]  += xk * w0.y;
                acc[i][2]  += xk * w0.z; acc[i][3]  += xk * w0.w;
                acc[i][4]  += xk * w1.x; acc[i][5]  += xk * w1.y;
                acc[i][6]  += xk * w1.z; acc[i][7]  += xk * w1.w;
                acc[i][8]  += xk * w2.x; acc[i][9]  += xk * w2.y;
                acc[i][10] += xk * w2.z; acc[i][11] += xk * w2.w;
                acc[i][12] += xk * w3.x; acc[i][13] += xk * w3.y;
                acc[i][14] += xk * w3.z; acc[i][15] += xk * w3.w;
            }
        }
    }

    // epilogue: bf16 store + att1 (pair lanes cg, cg^1 hold the two 16-col halves of head cg>>1)
    int head = cg >> 1;
    int half = cg & 1;
    float asv[16], adv[16];
#pragma unroll
    for (int j = 0; j < 16; ++j) {
        asv[j] = att_src[head * 32 + half * 16 + j];
        adv[j] = att_dst[head * 32 + half * 16 + j];
    }
#pragma unroll
    for (int i = 0; i < 4; ++i) {
        int r = r0 + i;
        float ps = 0.f, pd = 0.f;
#pragma unroll
        for (int j = 0; j < 16; ++j) {
            ps += acc[i][j] * asv[j];
            pd += acc[i][j] * adv[j];
        }
        ps += __shfl_xor(ps, 1, 64);
        pd += __shfl_xor(pd, 1, 64);
        if (r < N_NODES) {
            __hip_bfloat162* yp = (__hip_bfloat162*)(Y + (size_t)r * 128 + c0);
#pragma unroll
            for (int j = 0; j < 8; ++j) {
                __hip_bfloat162 p;
                p.x = __float2bfloat16(acc[i][2 * j]);
                p.y = __float2bfloat16(acc[i][2 * j + 1]);
                yp[j] = p;
            }
            if (half == 0) {
                a_s[r * 4 + head] = ps;
                a_d[r * 4 + head] = pd;
            }
        }
    }
}

// ---------------- scans ----------------
__global__ __launch_bounds__(256) void scan1_kernel(const int* __restrict__ deg,
                                                    int* __restrict__ rpl,
                                                    int* __restrict__ bsum) {
    int i = blockIdx.x * 256 + threadIdx.x;
    int v = (i < N_NODES) ? deg[i] : 0;
    int lane = threadIdx.x & 63;
    int w = threadIdx.x >> 6;
    int x = v;
#pragma unroll
    for (int off = 1; off < 64; off <<= 1) {
        int t = __shfl_up(x, off, 64);
        if (lane >= off) x += t;
    }
    __shared__ int wsum[4];
    if (lane == 63) wsum[w] = x;
    __syncthreads();
    int wo = 0;
    if (w > 0) wo += wsum[0];
    if (w > 1) wo += wsum[1];
    if (w > 2) wo += wsum[2];
    if (i <= N_NODES) rpl[i] = x - v + wo;
    if (threadIdx.x == 255) bsum[blockIdx.x] = x + wo;
}

__global__ __launch_bounds__(256) void scan2_kernel(const int* __restrict__ bsum,
                                                    int* __restrict__ boff) {
    int i = threadIdx.x;
    int v = (i < NB_SCAN) ? bsum[i] : 0;
    int lane = threadIdx.x & 63;
    int w = threadIdx.x >> 6;
    int x = v;
#pragma unroll
    for (int off = 1; off < 64; off <<= 1) {
        int t = __shfl_up(x, off, 64);
        if (lane >= off) x += t;
    }
    __shared__ int wsum[4];
    if (lane == 63) wsum[w] = x;
    __syncthreads();
    int wo = 0;
    if (w > 0) wo += wsum[0];
    if (w > 1) wo += wsum[1];
    if (w > 2) wo += wsum[2];
    if (i < NB_SCAN) boff[i] = x - v + wo;
}

// ---------------- scatter: 4 independent edges per thread ----------------
__global__ __launch_bounds__(256) void scatter_kernel(const int* __restrict__ src,
                                                      const int* __restrict__ dst,
                                                      const int* __restrict__ rpl,
                                                      const int* __restrict__ boff,
                                                      const int* __restrict__ rank,
                                                      int* __restrict__ col) {
    int base = blockIdx.x * 1024 + threadIdx.x;
    int idx[4], d[4], rk[4], sv[4];
#pragma unroll
    for (int u = 0; u < 4; ++u) {
        idx[u] = base + u * 256;
        int i = (idx[u] < N_EDGES) ? idx[u] : N_EDGES - 1;
        d[u] = dst[i];
        rk[u] = rank[i];
        sv[u] = src[i];
    }
    int pos[4];
#pragma unroll
    for (int u = 0; u < 4; ++u) pos[u] = rpl[d[u]] + boff[d[u] >> 8] + rk[u];
#pragma unroll
    for (int u = 0; u < 4; ++u)
        if (idx[u] < N_EDGES) col[pos[u]] = sv[u];
}

// ---------------- aggregation layer 1 ----------------
__global__ __launch_bounds__(256) void agg1_kernel(const __hip_bfloat16* __restrict__ h,
                                                   const float* __restrict__ a_s,
                                                   const float* __restrict__ a_d,
                                                   const int* __restrict__ rpl,
                                                   const int* __restrict__ boff,
                                                   const int* __restrict__ col,
                                                   const float* __restrict__ b1,
                                                   const float* __restrict__ gamma,
                                                   const float* __restrict__ beta,
                                                   float* __restrict__ out) {
    __shared__ int colsh[4][CAP];
    __shared__ float wsh[4][CAP * 4];
    int wv = threadIdx.x >> 6;
    int lane = threadIdx.x & 63;
    int n = blockIdx.x * 4 + wv;
    int nn = (n < N_NODES) ? n : N_NODES - 1;
    int head = lane >> 4;
    int c = 2 * lane;

    const float4 ad4 = *(const float4*)&a_d[nn * 4];
    int beg = rpl[nn] + boff[nn >> 8];
    int end = rpl[nn + 1] + boff[(nn + 1) >> 8];
    int deg = end - beg;

    float den0 = 0.f, den1 = 0.f, den2 = 0.f, den3 = 0.f;
    for (int t = lane; t < deg; t += 64) {
        int s = col[beg + t];
        const float4 as4 = *(const float4*)&a_s[s * 4];
        float w0 = __expf(lrelu(as4.x + ad4.x));
        float w1 = __expf(lrelu(as4.y + ad4.y));
        float w2 = __expf(lrelu(as4.z + ad4.z));
        float w3 = __expf(lrelu(as4.w + ad4.w));
        if (t < CAP) {
            colsh[wv][t] = s;
            *(float4*)&wsh[wv][t * 4] = make_float4(w0, w1, w2, w3);
        }
        den0 += w0; den1 += w1; den2 += w2; den3 += w3;
    }
#pragma unroll
    for (int m = 1; m < 64; m <<= 1) {
        den0 += __shfl_xor(den0, m, 64);
        den1 += __shfl_xor(den1, m, 64);
        den2 += __shfl_xor(den2, m, 64);
        den3 += __shfl_xor(den3, m, 64);
    }
    float adh = (head == 0) ? ad4.x : (head == 1) ? ad4.y : (head == 2) ? ad4.z : ad4.w;
    float wself = __expf(lrelu(a_s[nn * 4 + head] + adh));
    float den = ((head == 0) ? den0 : (head == 1) ? den1 : (head == 2) ? den2 : den3) + wself;

    __syncthreads();

    float ax0 = 0.f, ay0 = 0.f, ax1 = 0.f, ay1 = 0.f;
    int m0 = (deg < CAP) ? deg : CAP;
    int j = 0;
    for (; j + 3 < m0; j += 4) {
        int s0 = colsh[wv][j + 0], s1 = colsh[wv][j + 1];
        int s2 = colsh[wv][j + 2], s3 = colsh[wv][j + 3];
        float w0 = wsh[wv][(j + 0) * 4 + head], w1 = wsh[wv][(j + 1) * 4 + head];
        float w2 = wsh[wv][(j + 2) * 4 + head], w3 = wsh[wv][(j + 3) * 4 + head];
        __hip_bfloat162 h0 = ((const __hip_bfloat162*)h)[(size_t)s0 * 64 + lane];
        __hip_bfloat162 h1 = ((const __hip_bfloat162*)h)[(size_t)s1 * 64 + lane];
        __hip_bfloat162 h2v = ((const __hip_bfloat162*)h)[(size_t)s2 * 64 + lane];
        __hip_bfloat162 h3 = ((const __hip_bfloat162*)h)[(size_t)s3 * 64 + lane];
        ax0 += w0 * bf2f(h0.x); ay0 += w0 * bf2f(h0.y);
        ax1 += w1 * bf2f(h1.x); ay1 += w1 * bf2f(h1.y);
        ax0 += w2 * bf2f(h2v.x); ay0 += w2 * bf2f(h2v.y);
        ax1 += w3 * bf2f(h3.x); ay1 += w3 * bf2f(h3.y);
    }
    for (; j < m0; ++j) {
        int s = colsh[wv][j];
        float w = wsh[wv][j * 4 + head];
        __hip_bfloat162 hv = ((const __hip_bfloat162*)h)[(size_t)s * 64 + lane];
        ax0 += w * bf2f(hv.x); ay0 += w * bf2f(hv.y);
    }
    for (; j < deg; ++j) {
        int s = col[beg + j];
        float w = __expf(lrelu(a_s[s * 4 + head] + adh));
        __hip_bfloat162 hv = ((const __hip_bfloat162*)h)[(size_t)s * 64 + lane];
        ax0 += w * bf2f(hv.x); ay0 += w * bf2f(hv.y);
    }
    {
        __hip_bfloat162 hv = ((const __hip_bfloat162*)h)[(size_t)nn * 64 + lane];
        ax0 += wself * bf2f(hv.x); ay0 += wself * bf2f(hv.y);
    }
    float inv = 1.f / den;
    float vx = (ax0 + ax1) * inv + b1[c];
    float vy = (ay0 + ay1) * inv + b1[c + 1];

    float s1 = vx + vy, s2 = vx * vx + vy * vy;
#pragma unroll
    for (int m = 1; m < 64; m <<= 1) {
        s1 += __shfl_xor(s1, m, 64);
        s2 += __shfl_xor(s2, m, 64);
    }
    float mean = s1 * (1.f / 128.f);
    float var = s2 * (1.f / 128.f) - mean * mean;
    float r = rsqrtf(var + LN_EPS);
    float ox = fmaxf(0.f, (vx - mean) * r * gamma[c] + beta[c]);
    float oy = fmaxf(0.f, (vy - mean) * r * gamma[c + 1] + beta[c + 1]);
    if (n < N_NODES) *(float2*)&out[(size_t)n * 128 + c] = make_float2(ox, oy);
}

// ---------------- gemm2 + att2 epilogue (R4-proven mapping: cg = tid%4) ----------------
__global__ __launch_bounds__(256) void gemm2_att2_kernel(const float* __restrict__ X,
                                                         const float* __restrict__ W,
                                                         __hip_bfloat16* __restrict__ Y,
                                                         const float* __restrict__ att_src,
                                                         const float* __restrict__ att_dst,
                                                         float* __restrict__ a_s,
                                                         float* __restrict__ a_d) {
    constexpr int COLS = 64;
    constexpr int CG = 4, RPT = 2;
    __shared__ float Wlds[128 * COLS];  // 32 KB
    for (int i = threadIdx.x; i < 128 * COLS; i += 256) Wlds[i] = W[i];
    __syncthreads();

    int cg = threadIdx.x % CG;
    int rg = threadIdx.x / CG;
    int r0 = blockIdx.x * 128 + rg * RPT;
    int c0 = cg * 16;

    float acc[RPT][16];
#pragma unroll
    for (int i = 0; i < RPT; ++i)
#pragma unroll
        for (int j = 0; j < 16; ++j) acc[i][j] = 0.f;

    const float* xrow[RPT];
#pragma unroll
    for (int i = 0; i < RPT; ++i) {
        int ri = r0 + i;
        if (ri >= N_NODES) ri = N_NODES - 1;
        xrow[i] = X + (size_t)ri * 128;
    }

    for (int k = 0; k < 128; k += 4) {
        float4 xv[RPT];
#pragma unroll
        for (int i = 0; i < RPT; ++i) xv[i] = *(const float4*)&xrow[i][k];
#pragma unroll
        for (int kk = 0; kk < 4; ++kk) {
            const float* wrow = &Wlds[(k + kk) * COLS + c0];
            const float4 w0 = *(const float4*)(wrow + 0);
            const float4 w1 = *(const float4*)(wrow + 4);
            const float4 w2 = *(const float4*)(wrow + 8);
            const float4 w3 = *(const float4*)(wrow + 12);
#pragma unroll
            for (int i = 0; i < RPT; ++i) {
                float xk = (kk == 0) ? xv[i].x : (kk == 1) ? xv[i].y : (kk == 2) ? xv[i].z : xv[i].w;
                acc[i][0]  += xk * w0.x; acc[i][1]  += xk * w0.y;
                acc[i][2]  += xk * w0.z; acc[i][3]  += xk * w0.w;
                acc[i][4]  += xk * w1.x; acc[i][5]  += xk * w1.y;
                acc[i][6]  += xk * w1.z; acc[i][7]  += xk * w1.w;
                acc[i][8]  += xk * w2.x; acc[i][9]  += xk * w2.y;
                acc[i][10] += xk * w2.z; acc[i][11] += xk * w2.w;
                acc[i][12] += xk * w3.x; acc[i][13] += xk * w3.y;
                acc[i][14] += xk * w3.z; acc[i][15] += xk * w3.w;
            }
        }
    }

    float asv[16], adv[16];
#pragma unroll
    for (int j = 0; j < 16; ++j) {
        asv[j] = att_src[c0 + j];
        adv[j] = att_dst[c0 + j];
    }
#pragma unroll
    for (int i = 0; i < RPT; ++i) {
        int r = r0 + i;
        float ps = 0.f, pd = 0.f;
#pragma unroll
        for (int j = 0; j < 16; ++j) {
            ps += acc[i][j] * asv[j];
            pd += acc[i][j] * adv[j];
        }
        ps += __shfl_xor(ps, 1, 64);
        pd += __shfl_xor(pd, 1, 64);
        ps += __shfl_xor(ps, 2, 64);
        pd += __shfl_xor(pd, 2, 64);
        if (r < N_NODES) {
            __hip_bfloat162* yp = (__hip_bfloat162*)(Y + (size_t)r * COLS + c0);
#pragma unroll
            for (int j = 0; j < 8; ++j) {
                __hip_bfloat162 p;
                p.x = __float2bfloat16(acc[i][2 * j]);
                p.y = __float2bfloat16(acc[i][2 * j + 1]);
                yp[j] = p;
            }
            if (cg == 0) {
                a_s[r] = ps;
                a_d[r] = pd;
            }
        }
    }
}

// ---------------- aggregation layer 2 ----------------
__global__ __launch_bounds__(256) void agg2_kernel(const __hip_bfloat16* __restrict__ h,
                                                   const float* __restrict__ a_s,
                                                   const float* __restrict__ a_d,
                                                   const int* __restrict__ rpl,
                                                   const int* __restrict__ boff,
                                                   const int* __restrict__ col,
                                                   const float* __restrict__ b2,
                                                   const float* __restrict__ gamma,
                                                   const float* __restrict__ beta,
                                                   float* __restrict__ out) {
    __shared__ int colsh[4][CAP];
    __shared__ float wsh[4][CAP];
    int wv = threadIdx.x >> 6;
    int lane = threadIdx.x & 63;
    int n = blockIdx.x * 4 + wv;
    int nn = (n < N_NODES) ? n : N_NODES - 1;

    float adh = a_d[nn];
    int beg = rpl[nn] + boff[nn >> 8];
    int end = rpl[nn + 1] + boff[(nn + 1) >> 8];
    int deg = end - beg;

    float den = 0.f;
    for (int t = lane; t < deg; t += 64) {
        int s = col[beg + t];
        float w = __expf(lrelu(a_s[s] + adh));
        if (t < CAP) {
            colsh[wv][t] = s;
            wsh[wv][t] = w;
        }
        den += w;
    }
#pragma unroll
    for (int m = 1; m < 64; m <<= 1) den += __shfl_xor(den, m, 64);
    float wself = __expf(lrelu(a_s[nn] + adh));
    den += wself;

    __syncthreads();

    float a0 = 0.f, a1 = 0.f;
    int m0 = (deg < CAP) ? deg : CAP;
    int j = 0;
    for (; j + 3 < m0; j += 4) {
        int s0 = colsh[wv][j + 0], s1 = colsh[wv][j + 1];
        int s2 = colsh[wv][j + 2], s3 = colsh[wv][j + 3];
        float w0 = wsh[wv][j + 0], w1 = wsh[wv][j + 1];
        float w2 = wsh[wv][j + 2], w3 = wsh[wv][j + 3];
        a0 += w0 * bf2f(h[(size_t)s0 * 64 + lane]);
        a1 += w1 * bf2f(h[(size_t)s1 * 64 + lane]);
        a0 += w2 * bf2f(h[(size_t)s2 * 64 + lane]);
        a1 += w3 * bf2f(h[(size_t)s3 * 64 + lane]);
    }
    for (; j < m0; ++j) {
        a0 += wsh[wv][j] * bf2f(h[(size_t)colsh[wv][j] * 64 + lane]);
    }
    for (; j < deg; ++j) {
        int s = col[beg + j];
        float w = __expf(lrelu(a_s[s] + adh));
        a0 += w * bf2f(h[(size_t)s * 64 + lane]);
    }
    a0 += wself * bf2f(h[(size_t)nn * 64 + lane]);

    float v = (a0 + a1) / den + b2[lane];

    float s1 = v, s2 = v * v;
#pragma unroll
    for (int m = 1; m < 64; m <<= 1) {
        s1 += __shfl_xor(s1, m, 64);
        s2 += __shfl_xor(s2, m, 64);
    }
    float mean = s1 * (1.f / 64.f);
    float var = s2 * (1.f / 64.f) - mean * mean;
    float r = rsqrtf(var + LN_EPS);
    if (n < N_NODES) out[(size_t)n * 64 + lane] = (v - mean) * r * gamma[lane] + beta[lane];
}

// ---------------- host ----------------
extern "C" void kernel_launch(void* const* d_in, const int* in_sizes, int n_in,
                              void* d_out, int out_size, void* d_ws, size_t ws_size,
                              hipStream_t stream) {
    const float* x        = (const float*)d_in[0];
    const int*   ei       = (const int*)d_in[1];
    const float* W1       = (const float*)d_in[2];
    const float* att_src1 = (const float*)d_in[3];
    const float* att_dst1 = (const float*)d_in[4];
    const float* b1       = (const float*)d_in[5];
    const float* gamma1   = (const float*)d_in[6];
    const float* beta1    = (const float*)d_in[7];
    const float* W2       = (const float*)d_in[8];
    const float* att_src2 = (const float*)d_in[9];
    const float* att_dst2 = (const float*)d_in[10];
    const float* b2       = (const float*)d_in[11];
    const float* gamma2   = (const float*)d_in[12];
    const float* beta2    = (const float*)d_in[13];
    const int* src = ei;
    const int* dst = ei + N_EDGES;
    float* out = (float*)d_out;

    char* ws = (char*)d_ws;
    size_t off = 0;
    auto alloc = [&](size_t bytes) -> void* {
        void* p = ws + off;
        off += bytes;
        off = (off + 255) & ~(size_t)255;
        return p;
    };
    __hip_bfloat16* h1pre = (__hip_bfloat16*)alloc((size_t)N_NODES * 128 * 2);
    __hip_bfloat16* h2pre = (__hip_bfloat16*)alloc((size_t)N_NODES * 64 * 2);
    float* a_s1   = (float*)alloc((size_t)N_NODES * 4 * 4);
    float* a_d1   = (float*)alloc((size_t)N_NODES * 4 * 4);
    float* h1n    = (float*)alloc((size_t)N_NODES * 128 * 4);
    float* a_s2   = (float*)alloc((size_t)N_NODES * 4);
    float* a_d2   = (float*)alloc((size_t)N_NODES * 4);
    int* deg      = (int*)alloc((size_t)N_NODES * 4);
    int* rpl      = (int*)alloc((size_t)(N_NODES + 1) * 4);
    int* col      = (int*)alloc((size_t)N_EDGES * 4);
    int* rank     = (int*)alloc((size_t)N_EDGES * 4);
    int* bsum     = (int*)alloc((size_t)NB_SCAN * 4);
    int* boff     = (int*)alloc((size_t)NB_SCAN * 4);

    hipMemsetAsync(deg, 0, (size_t)N_NODES * 4, stream);

    const int NWB = (N_NODES + 3) / 4;
    const int SCB = (N_EDGES + 1023) / 1024;

    gemm1_att1_degree_kernel<<<GB1 + DEGB, 512, 0, stream>>>(
        x, W1, h1pre, att_src1, att_dst1, a_s1, a_d1, dst, deg, rank);
    scan1_kernel<<<NB_SCAN, 256, 0, stream>>>(deg, rpl, bsum);
    scan2_kernel<<<1, 256, 0, stream>>>(bsum, boff);
    scatter_kernel<<<SCB, 256, 0, stream>>>(src, dst, rpl, boff, rank, col);

    agg1_kernel<<<NWB, 256, 0, stream>>>(h1pre, a_s1, a_d1, rpl, boff, col, b1, gamma1, beta1, h1n);

    gemm2_att2_kernel<<<(N_NODES + 127) / 128, 256, 0, stream>>>(
        h1n, W2, h2pre, att_src2, att_dst2, a_s2, a_d2);
    agg2_kernel<<<NWB, 256, 0, stream>>>(h2pre, a_s2, a_d2, rpl, boff, col, b2, gamma2, beta2, out);
}